// Round 14
// baseline (67.053 us; speedup 1.0000x reference)
//
#include <hip/hip_runtime.h>
#include <math.h>

#define HW1 (1024 * 1024)
#define WID 1024
#define HEI 1024
#define NMAIN 512            // (gy 0..255) x (h 0..1)

typedef float f32x4 __attribute__((ext_vector_type(4)));
typedef _Float16 f16;

// Block-level reduce (wave shfl + LDS) then one atomicAdd per block.
__device__ __forceinline__ void block_atomic_add(float v, float* target, volatile float* sdata) {
#pragma unroll
    for (int off = 32; off > 0; off >>= 1)
        v += __shfl_down(v, off, 64);
    const int lane = threadIdx.x & 63;
    const int wv   = threadIdx.x >> 6;
    if (lane == 0) sdata[wv] = v;
    __syncthreads();
    if (threadIdx.x == 0) {
        float s = 0.f;
        for (int i = 0; i < 4; ++i) s += sdata[i];
        atomicAdd(target, s);
    }
    __syncthreads();
}

// ONE worker kernel, zero global intermediates, sobel fused in-block.
// Block=(gy,h): 4 image rows x 512 cols, ALL 3 channels, ALL 8 batches.
//  - r_loss, c_loss thread-local (channels in-thread)
//  - pd (pooled diff, f16) -> LDS [8][3][4][130] w/ ghost cols; p_loss in-block
//  - batch-0 diff d=A-B (f16) -> LDS [3][6][528] (rows 4gy-1..4gy+4, cols -8..519);
//    halo rows/cols loaded in epilogue; sobel s_loss computed in-block.
__global__ __launch_bounds__(256) void k_A(const float* __restrict__ A,
                                           const float* __restrict__ B,
                                           float* __restrict__ acc) {
    __shared__ f16 pd[8][3][4][130];   // [b][c][yl][slot]; slot 1..128 data, 0/129 ghost
    __shared__ f16 dsh[3][6][528];     // [c][r][slot]; r: y=4gy-1+r; slot = local_col+8
    __shared__ float s1[4];

    const int tid = threadIdx.x;
    const int gy = blockIdx.x >> 1;      // pool row 0..255
    const int h  = blockIdx.x & 1;       // half-row
    const int xl = tid & 63;
    const int yl = tid >> 6;             // image row within pool row
    const int y  = gy * 4 + yl;
    const int rbase = y * 256 + h * 128; // float4 index of this half-row

    const f32x4* A4 = reinterpret_cast<const f32x4*>(A);
    const f32x4* B4 = reinterpret_cast<const f32x4*>(B);

    // zero dsh (halo slots must default to conv zero-pad)
    {
        unsigned* dz = reinterpret_cast<unsigned*>(&dsh[0][0][0]);
        for (int i = tid; i < 3 * 6 * 528 / 2; i += 256) dz[i] = 0u;
    }
    __syncthreads();

    float na2[3][8], nb2[3][8], dt[3][8];   // [c][pixel] — static indexing
#pragma unroll
    for (int c = 0; c < 3; ++c)
#pragma unroll
        for (int j = 0; j < 8; ++j) { na2[c][j] = 0.f; nb2[c][j] = 0.f; dt[c][j] = 0.f; }
    float r_sum = 0.f;

    // ---- b = 0 peel: also capture d = A-B into dsh ----
#pragma unroll
    for (int c = 0; c < 3; ++c) {
        const int pbase = c * (HW1 / 4) + rbase;
        const f32x4 a0 = A4[pbase + xl];
        const f32x4 a1 = A4[pbase + 64 + xl];
        const f32x4 b0 = B4[pbase + xl];
        const f32x4 b1 = B4[pbase + 64 + xl];
        float pd0 = 0.f, pd1 = 0.f;
#pragma unroll
        for (int j = 0; j < 4; ++j) {
            const float a = a0[j], t = b0[j];
            na2[c][j] += a * a; nb2[c][j] += t * t; dt[c][j] += a * t;
            r_sum += fabsf(a - t); pd0 += t - a;
            dsh[c][yl + 1][8 + 4 * xl + j] = (f16)(a - t);
        }
#pragma unroll
        for (int j = 0; j < 4; ++j) {
            const float a = a1[j], t = b1[j];
            na2[c][4 + j] += a * a; nb2[c][4 + j] += t * t; dt[c][4 + j] += a * t;
            r_sum += fabsf(a - t); pd1 += t - a;
            dsh[c][yl + 1][8 + 256 + 4 * xl + j] = (f16)(a - t);
        }
        pd[0][c][yl][1 + xl]  = (f16)pd0;
        pd[0][c][yl][65 + xl] = (f16)pd1;
    }

    // ---- b = 1..7 hot loop (branch-free) ----
#pragma unroll 2
    for (int b = 1; b < 8; ++b) {
#pragma unroll
        for (int c = 0; c < 3; ++c) {
            const int pbase = (b * 3 + c) * (HW1 / 4) + rbase;
            const f32x4 a0 = A4[pbase + xl];
            const f32x4 a1 = A4[pbase + 64 + xl];
            const f32x4 b0 = B4[pbase + xl];
            const f32x4 b1 = B4[pbase + 64 + xl];
            float pd0 = 0.f, pd1 = 0.f;
#pragma unroll
            for (int j = 0; j < 4; ++j) {
                const float a = a0[j], t = b0[j];
                na2[c][j] += a * a; nb2[c][j] += t * t; dt[c][j] += a * t;
                r_sum += fabsf(a - t); pd0 += t - a;
            }
#pragma unroll
            for (int j = 0; j < 4; ++j) {
                const float a = a1[j], t = b1[j];
                na2[c][4 + j] += a * a; nb2[c][4 + j] += t * t; dt[c][4 + j] += a * t;
                r_sum += fabsf(a - t); pd1 += t - a;
            }
            pd[b][c][yl][1 + xl]  = (f16)pd0;
            pd[b][c][yl][65 + xl] = (f16)pd1;
        }
    }

    // ---- epilogue A: pd ghost columns (G-channel neighbor cells) ----
    if (tid < 192) {
        const int side = tid & 1;            // 0 = slot 0, 1 = slot 129
        const int yl2  = (tid >> 1) & 3;
        const int c2   = (tid >> 3) % 3;
        const int b2   = tid / 24;
        const int dataside = (h == 0) ? 1 : 0;
        if (!(c2 == 1 && side == dataside))
            pd[b2][c2][yl2][side ? 129 : 0] = (f16)0.f;
    } else if (tid < 224) {
        const int i2  = tid - 192;
        const int b2  = i2 >> 2;
        const int yl2 = i2 & 3;
        const int gcol = (h == 0) ? 128 : 127;   // neighbor pool cell's float4 col
        const int slot = (h == 0) ? 129 : 0;
        const int gp = (b2 * 3 + 1) * (HW1 / 4) + (gy * 4 + yl2) * 256 + gcol;
        const f32x4 ga = A4[gp];
        const f32x4 gb = B4[gp];
        pd[b2][1][yl2][slot] = (f16)((gb[0] - ga[0]) + (gb[1] - ga[1])
                                   + (gb[2] - ga[2]) + (gb[3] - ga[3]));
    }

    // ---- epilogue B: dsh halo (2 rows x 130 f4 x 3 ch) + main-row col halos ----
    for (int i = tid; i < 804; i += 256) {
        int c2, r2, f4, yy;
        if (i < 780) {
            const int f_rel = i % 130;
            const int rc    = i / 130;          // 0..5 = (2 rows) x (3 ch)
            const int rr    = rc & 1;
            c2 = rc >> 1;
            r2 = rr ? 5 : 0;
            f4 = h * 128 - 1 + f_rel;
            yy = rr ? (gy * 4 + 4) : (gy * 4 - 1);
        } else {
            const int i2 = i - 780;             // 0..23
            const int side = i2 & 1;
            const int yl2  = (i2 >> 1) & 3;
            c2 = i2 >> 3;
            r2 = yl2 + 1;
            f4 = h * 128 + (side ? 128 : -1);
            yy = gy * 4 + yl2;
        }
        if (f4 >= 0 && f4 < 256 && yy >= 0 && yy < HEI) {
            const int gp = c2 * (HW1 / 4) + yy * 256 + f4;
            const f32x4 ga = A4[gp];
            const f32x4 gb = B4[gp];
            const int sbase = 4 * (f4 - 128 * h) + 8;
#pragma unroll
            for (int j = 0; j < 4; ++j)
                dsh[c2][r2][sbase + j] = (f16)(ga[j] - gb[j]);
        }
    }

    // ---- c_loss: thread-local over its 8 pixels ----
    float c_sum = 0.f;
#pragma unroll
    for (int j = 0; j < 8; ++j) {
        float cs = 0.f;
#pragma unroll
        for (int c = 0; c < 3; ++c) {
            const float na = fmaxf(sqrtf(na2[c][j]), 1e-12f);
            const float nb = fmaxf(sqrtf(nb2[c][j]), 1e-12f);
            cs += dt[c][j] / (na * nb);
        }
        cs = fminf(fmaxf(cs, -1.0f + 1e-7f), 1.0f - 1e-7f);
        c_sum += acosf(cs);
    }

    __syncthreads();

    // ---- p_loss in-block: 8 b x 128 cells = 1024 items, 4/thread ----
    float p_sum = 0.f;
#pragma unroll
    for (int i = 0; i < 4; ++i) {
        const int item = i * 256 + tid;
        const int b2 = item >> 7;
        const int x  = item & 127;
        float g = 0.f, gl = 0.f, gr = 0.f, rr = 0.f, bb = 0.f;
#pragma unroll
        for (int yy = 0; yy < 4; ++yy) {
            g  += (float)pd[b2][1][yy][1 + x];
            gl += (float)pd[b2][1][yy][x];
            gr += (float)pd[b2][1][yy][2 + x];
            rr += (float)pd[b2][0][yy][1 + x];
            bb += (float)pd[b2][2][yy][1 + x];
        }
        const float d0 = g - gl;
        const float d1 = g - gr;
        const float d2 = g - rr;
        const float d3 = g - bb;
        p_sum += d0 * d0 + d1 * d1 + d2 * d2 + d3 * d3;
    }
    p_sum *= (1.0f / 256.0f);

    // ---- sobel in-block: 3 ch x 4 rows x 512 cols = 6144 outputs, 24/thread ----
    float s_sum = 0.f;
#pragma unroll
    for (int i = 0; i < 24; ++i) {
        const int idx = i * 256 + tid;
        const int c2  = idx >> 11;
        const int row = (idx >> 9) & 3;     // output image row = 4gy+row -> dsh rows row..row+2
        const int col = idx & 511;
        const int s0  = col + 8;
        const float rd0 = (float)dsh[c2][row][s0 - 1]     - (float)dsh[c2][row][s0 + 1];
        const float rd1 = (float)dsh[c2][row + 1][s0 - 1] - (float)dsh[c2][row + 1][s0 + 1];
        const float rd2 = (float)dsh[c2][row + 2][s0 - 1] - (float)dsh[c2][row + 2][s0 + 1];
        s_sum += fabsf(rd0 + 2.f * rd1 + rd2);
    }

    block_atomic_add(r_sum, acc + 0, s1);
    block_atomic_add(c_sum, acc + 1, s1);
    block_atomic_add(s_sum, acc + 2, s1);
    block_atomic_add(p_sum, acc + 3, s1);
}

// Combine: out = W_C*c + W_R*r + W_P*p + W_S*s
__global__ void k_final(const float* __restrict__ acc, float* __restrict__ out) {
    const float r = acc[0] * (1.0f / 25165824.0f);  // mean over 8*3*1024*1024
    const float c = acc[1];
    const float s = acc[2];
    const float p = acc[3] * (1.0f / 524288.0f);    // mean over 8*256*256
    out[0] = 0.5f * c + 1.0f * r + 1.0f * p + 0.1f * s;
}

extern "C" void kernel_launch(void* const* d_in, const int* in_sizes, int n_in,
                              void* d_out, int out_size, void* d_ws, size_t ws_size,
                              hipStream_t stream) {
    const float* A = (const float*)d_in[0];  // predictions
    const float* B = (const float*)d_in[1];  // targets
    float* acc = (float*)d_ws;               // acc[0..3]

    hipMemsetAsync(acc, 0, 64 * sizeof(float), stream);
    hipLaunchKernelGGL(k_A,     dim3(NMAIN), dim3(256), 0, stream, A, B, acc);
    hipLaunchKernelGGL(k_final, dim3(1),     dim3(1),   0, stream, acc, (float*)d_out);
}